// Round 12
// baseline (306.917 us; speedup 1.0000x reference)
//
#include <hip/hip_runtime.h>
#include <cstdint>
#include <cstddef>

constexpr int N = 50000;
constexpr int E = 800000;
constexpr int D = 256;
constexpr float EPS = 1e-5f;
constexpr int NB = (N + 255) / 256;   // 196 scan blocks
constexpr int GB = (N + 63) / 64;     // 782 GEMM blocks
constexpr int CB = (E + 255) / 256;   // 3125 edge blocks (256 thr)
constexpr int CB64 = (E + 63) / 64;   // 12500 count blocks (64 thr)
constexpr int AGG_BLOCKS = 2048;      // fixed agg grid (grid-stride)

typedef __attribute__((ext_vector_type(8))) short short8;            // 8 bf16
typedef __attribute__((ext_vector_type(4))) float f32x4;             // MFMA acc / nt-store

// ---- bf16 helpers ----
__device__ __forceinline__ unsigned short f2bf(float f) {  // RNE (scalar path)
  union { float f; unsigned u; } c; c.f = f;
  unsigned u = c.u;
  u += 0x7fff + ((u >> 16) & 1);
  return (unsigned short)(u >> 16);
}
__device__ __forceinline__ float bf2f(unsigned short h) {
  union { unsigned u; float f; } c; c.u = ((unsigned)h) << 16;
  return c.f;
}
__device__ __forceinline__ float bflo(unsigned u) {
  union { unsigned x; float f; } c; c.x = u << 16; return c.f;
}
__device__ __forceinline__ float bfhi(unsigned u) {
  union { unsigned x; float f; } c; c.x = u & 0xffff0000u; return c.f;
}
// HW packed convert: dst = bf16(lo) | bf16(hi)<<16  (RNE; 1 VALU per 2 values)
__device__ __forceinline__ unsigned cvt_pk(float lo, float hi) {
  unsigned r;
  asm("v_cvt_pk_bf16_f32 %0, %1, %2" : "=v"(r) : "v"(lo), "v"(hi));
  return r;
}
// nontemporal 8B edge-pair load
__device__ __forceinline__ int2 ldnt_pair(const int2* p) {
  unsigned long long v = __builtin_nontemporal_load((const unsigned long long*)p);
  int2 r;
  r.x = (int)(unsigned)(v & 0xffffffffull);
  r.y = (int)(unsigned)(v >> 32);
  return r;
}

// ---- inline edge-index dtype detection (per-wave, uniform) ----
__device__ __forceinline__ int detect64(const void* ei) {
  const int* p = (const int*)ei;
  int l = threadIdx.x & 63;
  int nz = (p[2 * l + 1] != 0) | (p[2 * l + 129] != 0);
  return __ballot(nz) == 0ULL;
}

__device__ __forceinline__ int edge_at(const void* ei, int is64, long long pos) {
  if (is64) return (int)((const long long*)ei)[pos];
  return ((const int*)ei)[pos];
}

// ---------------- GEMM body: C[64 rows x 256](bf16) = A @ W ----------------
template <bool A_BF16, bool FUSE_BN>
__device__ __forceinline__ void gemm_body(const void* __restrict__ Ap,
                                          const unsigned short* __restrict__ Wf,
                                          unsigned short* __restrict__ C,
                                          const float* __restrict__ sc,
                                          const float* __restrict__ sh,
                                          int bid) {
  __shared__ unsigned short As[64][264];   // [m][k] +8 pad; reused as Cs
  int t = threadIdx.x;
  int lane = t & 63;
  int w = t >> 6;
  int row0 = bid * 64;
  int l16 = lane & 15, lk = lane >> 4;

  f32x4 acc[4][4];
#pragma unroll
  for (int i = 0; i < 4; ++i)
#pragma unroll
    for (int j = 0; j < 4; ++j) acc[i][j] = (f32x4){0.f, 0.f, 0.f, 0.f};

  int arow = t >> 2;          // 0..63
  int ak0 = (t & 3) * 8;      // 0,8,16,24
  int gr = row0 + arow;
  bool inb = (gr < N);

#pragma unroll
  for (int ks = 0; ks < 8; ++ks) {
    int kc = ks * 32 + ak0;
    float f[8] = {0.f, 0.f, 0.f, 0.f, 0.f, 0.f, 0.f, 0.f};
    if (inb) {
      if (A_BF16) {
        const unsigned short* A = (const unsigned short*)Ap;
        short8 v = *(const short8*)&A[(size_t)gr * 256 + kc];
#pragma unroll
        for (int j = 0; j < 8; ++j) f[j] = bf2f((unsigned short)v[j]);
      } else {
        const float* A = (const float*)Ap;
        float4 f0 = *(const float4*)&A[(size_t)gr * 256 + kc];
        float4 f1 = *(const float4*)&A[(size_t)gr * 256 + kc + 4];
        f[0] = f0.x; f[1] = f0.y; f[2] = f0.z; f[3] = f0.w;
        f[4] = f1.x; f[5] = f1.y; f[6] = f1.z; f[7] = f1.w;
      }
    }
    if (FUSE_BN) {
#pragma unroll
      for (int j = 0; j < 8; ++j)
        f[j] = fmaxf(fmaf(f[j], sc[kc + j], sh[kc + j]), 0.f);
    }
    uint4 pk;
    pk.x = cvt_pk(f[0], f[1]);
    pk.y = cvt_pk(f[2], f[3]);
    pk.z = cvt_pk(f[4], f[5]);
    pk.w = cvt_pk(f[6], f[7]);
    *(uint4*)&As[arow][kc] = pk;
  }
  __syncthreads();

#pragma unroll
  for (int ks = 0; ks < 8; ++ks) {
    short8 af[4];
#pragma unroll
    for (int mf = 0; mf < 4; ++mf)
      af[mf] = *(const short8*)&As[mf * 16 + l16][ks * 32 + lk * 8];
#pragma unroll
    for (int nf = 0; nf < 4; ++nf) {
      short8 bf = *(const short8*)&Wf[(((size_t)ks * 16 + w * 4 + nf) * 64 + lane) * 8];
#pragma unroll
      for (int mf = 0; mf < 4; ++mf)
        acc[mf][nf] = __builtin_amdgcn_mfma_f32_16x16x32_bf16(af[mf], bf, acc[mf][nf], 0, 0, 0);
    }
  }
  __syncthreads();  // As reads done; safe to alias as Cs

  unsigned short(*Cs)[264] = As;
#pragma unroll
  for (int mf = 0; mf < 4; ++mf)
#pragma unroll
    for (int nf = 0; nf < 4; ++nf)
#pragma unroll
      for (int r = 0; r < 4; ++r)
        Cs[mf * 16 + lk * 4 + r][w * 64 + nf * 16 + l16] = f2bf(acc[mf][nf][r]);
  __syncthreads();
#pragma unroll
  for (int it = 0; it < 8; ++it) {
    int r = it * 8 + (t >> 5);
    int gr2 = row0 + r;
    if (gr2 < N)
      *(short8*)&C[(size_t)gr2 * 256 + (t & 31) * 8] = *(const short8*)&Cs[r][(t & 31) * 8];
  }
}

// ---------------- GEMM layer 1 (fp32 A) ----------------
__global__ __launch_bounds__(256) void k_gemm1(const float* __restrict__ x,
                                               const unsigned short* __restrict__ Wf,
                                               unsigned short* __restrict__ C) {
  gemm_body<false, false>(x, Wf, C, nullptr, nullptr, blockIdx.x);
}

// ---------------- GEMM layer 2 (bf16 A, fused BN1+ReLU) ----------------
__global__ __launch_bounds__(256) void k_gemm2(const unsigned short* __restrict__ A,
                                               const unsigned short* __restrict__ Wf,
                                               unsigned short* __restrict__ C,
                                               const float* __restrict__ sc,
                                               const float* __restrict__ sh) {
  gemm_body<true, true>(A, Wf, C, sc, sh, blockIdx.x);
}

// ---------------- merged: W repack (both) + degree count ----------------
// 64-thread blocks, no LDS, low VGPR -> full occupancy for the atomic-bound
// count; wfrag (256 blocks) overlaps. degc is zeroed by the preceding memset.
__global__ __launch_bounds__(64) void k_wfrag_count(
    const float* __restrict__ W1, const float* __restrict__ W2,
    unsigned short* __restrict__ Wf1, unsigned short* __restrict__ Wf2,
    const void* __restrict__ ei, int* __restrict__ degc) {
  int b = blockIdx.x;
  if (b >= 256) {
    int is64 = detect64(ei);
    int e = (b - 256) * 64 + threadIdx.x;
    if (e >= E) return;
    int c = edge_at(ei, is64, (long long)E + e);
    atomicAdd(&degc[c], 1);
    return;
  }
  const float* W = (b < 128) ? W1 : W2;
  unsigned short* Wf = (b < 128) ? Wf1 : Wf2;
  int tile = b & 127;
  int lane = threadIdx.x;     // 64
  int kstep = tile >> 4, wn = tile & 15;
  int kbase = kstep * 32 + (lane >> 4) * 8;
  int col = wn * 16 + (lane & 15);
  float f[8];
#pragma unroll
  for (int j = 0; j < 8; ++j) f[j] = W[(size_t)(kbase + j) * 256 + col];
  uint4 pk;
  pk.x = cvt_pk(f[0], f[1]);
  pk.y = cvt_pk(f[2], f[3]);
  pk.z = cvt_pk(f[4], f[5]);
  pk.w = cvt_pk(f[6], f[7]);
  *(uint4*)&Wf[(((size_t)tile) * 64 + lane) * 8] = pk;
}

// ---------------- fused scan: partial sums -> spin -> full scan + self-fill ----
// 196 blocks (<= 256 CUs -> all co-resident; spin on a device atomic is safe).
__global__ __launch_bounds__(256) void k_scan(const int* __restrict__ degc,
                                              float* __restrict__ dinv,
                                              int* __restrict__ offs,
                                              int* __restrict__ curs,
                                              int2* __restrict__ epair,
                                              int* __restrict__ bsum,
                                              int* __restrict__ done) {
  __shared__ int sd[256];
  __shared__ int sb[256];
  int t = threadIdx.x;
  int i = blockIdx.x * 256 + t;
  int dv = (i < N) ? degc[i] : 0;
  float di = rsqrtf((float)(dv + 1));
  if (i < N) dinv[i] = di;
  int v = (i < N) ? (dv + 1) : 0;

  // phase A: per-block sum
  sd[t] = v;
  __syncthreads();
  for (int s = 128; s > 0; s >>= 1) {
    if (t < s) sd[t] += sd[t + s];
    __syncthreads();
  }
  if (t == 0) {
    bsum[blockIdx.x] = sd[0];
    __threadfence();
    atomicAdd(done, 1);
    while (atomicAdd(done, 0) < NB) { __builtin_amdgcn_s_sleep(1); }
  }
  __syncthreads();

  // phase B: prefix over bsum (values are call-invariant => replay-safe reads)
  int bv = (t < NB) ? bsum[t] : 0;
  sb[t] = bv;
  __syncthreads();
  for (int off = 1; off < 256; off <<= 1) {
    int x = (t >= off) ? sb[t - off] : 0;
    __syncthreads();
    sb[t] += x;
    __syncthreads();
  }
  int base = sb[blockIdx.x] - bsum[blockIdx.x];

  // element scan (recompute; sd was destroyed by the reduction)
  sd[t] = v;
  __syncthreads();
  for (int off = 1; off < 256; off <<= 1) {
    int x = (t >= off) ? sd[t - off] : 0;
    __syncthreads();
    sd[t] += x;
    __syncthreads();
  }
  if (i < N) {
    int o = base + sd[t] - v;
    offs[i] = o;
    curs[i] = o + 1;
    epair[o] = make_int2(i, __float_as_int(di * di));  // self loop
  }
  if (i == N - 1) offs[N] = base + sd[t];
}

__global__ void k_fill_edges(const void* __restrict__ ei,
                             const float* __restrict__ dinv, int* __restrict__ curs,
                             int2* __restrict__ epair) {
  int is64 = detect64(ei);
  int e = blockIdx.x * 256 + threadIdx.x;
  if (e >= E) return;
  int r = edge_at(ei, is64, e);
  int c = edge_at(ei, is64, (long long)E + e);
  int p = atomicAdd(&curs[c], 1);
  epair[p] = make_int2(r, __float_as_int(dinv[r] * dinv[c]));
}

// ---------------- aggregation + fused BN column stats ----------------
__global__ __launch_bounds__(256) void k_agg(const unsigned short* __restrict__ h,
                                             const int* __restrict__ offs,
                                             const int2* __restrict__ epair,
                                             const float* __restrict__ bias,
                                             unsigned short* __restrict__ outp,
                                             float* __restrict__ partial) {
  int t = threadIdx.x;
  int wv = t >> 6;
  int lane = t & 63;
  float4 bb = ((const float4*)bias)[lane];
  float s0 = 0.f, s1 = 0.f, s2 = 0.f, s3 = 0.f;
  float q0 = 0.f, q1 = 0.f, q2 = 0.f, q3 = 0.f;

#define ACC4(v, wgt)                         \
  do {                                       \
    a0 = fmaf(wgt, bflo((v).x), a0);         \
    a1 = fmaf(wgt, bfhi((v).x), a1);         \
    a2 = fmaf(wgt, bflo((v).y), a2);         \
    a3 = fmaf(wgt, bfhi((v).y), a3);         \
  } while (0)

  for (int nd0 = blockIdx.x * 4; nd0 < N; nd0 += AGG_BLOCKS * 4) {
    int nd = nd0 + wv;
    if (nd < N) {
      int node = __builtin_amdgcn_readfirstlane(nd);  // wave-uniform
      int e = offs[node];
      int end = offs[node + 1];
      float a0 = 0.f, a1 = 0.f, a2 = 0.f, a3 = 0.f;

      for (; e + 8 <= end; e += 8) {
        int2 p0 = ldnt_pair(&epair[e + 0]), p1 = ldnt_pair(&epair[e + 1]);
        int2 p2 = ldnt_pair(&epair[e + 2]), p3 = ldnt_pair(&epair[e + 3]);
        int2 p4 = ldnt_pair(&epair[e + 4]), p5 = ldnt_pair(&epair[e + 5]);
        int2 p6 = ldnt_pair(&epair[e + 6]), p7 = ldnt_pair(&epair[e + 7]);
        uint2 v0 = *(const uint2*)&h[(size_t)p0.x * 256 + lane * 4];
        uint2 v1 = *(const uint2*)&h[(size_t)p1.x * 256 + lane * 4];
        uint2 v2 = *(const uint2*)&h[(size_t)p2.x * 256 + lane * 4];
        uint2 v3 = *(const uint2*)&h[(size_t)p3.x * 256 + lane * 4];
        uint2 v4 = *(const uint2*)&h[(size_t)p4.x * 256 + lane * 4];
        uint2 v5 = *(const uint2*)&h[(size_t)p5.x * 256 + lane * 4];
        uint2 v6 = *(const uint2*)&h[(size_t)p6.x * 256 + lane * 4];
        uint2 v7 = *(const uint2*)&h[(size_t)p7.x * 256 + lane * 4];
        ACC4(v0, __int_as_float(p0.y));
        ACC4(v1, __int_as_float(p1.y));
        ACC4(v2, __int_as_float(p2.y));
        ACC4(v3, __int_as_float(p3.y));
        ACC4(v4, __int_as_float(p4.y));
        ACC4(v5, __int_as_float(p5.y));
        ACC4(v6, __int_as_float(p6.y));
        ACC4(v7, __int_as_float(p7.y));
      }
      if (e < end) {
#pragma unroll
        for (int k = 0; k < 8; ++k) {
          int idx = e + k;
          bool act = (idx < end);
          int2 p = ldnt_pair(&epair[act ? idx : end - 1]);  // deg >= 1
          float wgt = act ? __int_as_float(p.y) : 0.f;
          uint2 v = *(const uint2*)&h[(size_t)p.x * 256 + lane * 4];
          ACC4(v, wgt);
        }
      }

      uint2 ov;
      ov.x = cvt_pk(a0 + bb.x, a1 + bb.y);
      ov.y = cvt_pk(a2 + bb.z, a3 + bb.w);
      *(uint2*)&outp[(size_t)nd * 256 + lane * 4] = ov;
      float f0 = bflo(ov.x), f1 = bfhi(ov.x), f2v = bflo(ov.y), f3 = bfhi(ov.y);
      s0 += f0; q0 = fmaf(f0, f0, q0);
      s1 += f1; q1 = fmaf(f1, f1, q1);
      s2 += f2v; q2 = fmaf(f2v, f2v, q2);
      s3 += f3; q3 = fmaf(f3, f3, q3);
    }
  }
#undef ACC4

  __shared__ float4 ps[256];
  __shared__ float4 pq[256];
  ps[t] = {s0, s1, s2, s3};
  pq[t] = {q0, q1, q2, q3};
  __syncthreads();
  float* pout = partial + (size_t)blockIdx.x * 512;
  if (t < 64) {
    float4 a = ps[t], b = ps[64 + t], c = ps[128 + t], d = ps[192 + t];
    float4 o = {a.x + b.x + c.x + d.x, a.y + b.y + c.y + d.y,
                a.z + b.z + c.z + d.z, a.w + b.w + c.w + d.w};
    ((float4*)pout)[t] = o;
  } else if (t < 128) {
    int l = t - 64;
    float4 a = pq[l], b = pq[64 + l], c = pq[128 + l], d = pq[192 + l];
    float4 o = {a.x + b.x + c.x + d.x, a.y + b.y + c.y + d.y,
                a.z + b.z + c.z + d.z, a.w + b.w + c.w + d.w};
    ((float4*)(pout + 256))[l] = o;
  }
}

// ---------------- BN stats reduce + last-block finalize ----------------
__global__ __launch_bounds__(256) void k_bnred(const float* __restrict__ partial,
                                               float* __restrict__ bnsum,
                                               float* __restrict__ bnsq,
                                               int* __restrict__ cnt,
                                               const float* __restrict__ g,
                                               const float* __restrict__ be,
                                               float* __restrict__ sc,
                                               float* __restrict__ sh) {
  int t = threadIdx.x;
  float s = 0.f, q = 0.f;
  int b0 = blockIdx.x * (AGG_BLOCKS / 16);
  for (int b = b0; b < b0 + AGG_BLOCKS / 16; ++b) {
    s += partial[(size_t)b * 512 + t];
    q += partial[(size_t)b * 512 + 256 + t];
  }
  atomicAdd(&bnsum[t], s);
  atomicAdd(&bnsq[t], q);
  __threadfence();
  __shared__ int last;
  if (t == 0) last = (atomicAdd(cnt, 1) == 15);
  __syncthreads();
  if (last) {
    float S = atomicAdd(&bnsum[t], 0.f);  // device-coherent read
    float Q = atomicAdd(&bnsq[t], 0.f);
    const float inv = 1.f / (float)N;
    float m = S * inv;
    float v = Q * inv - m * m;
    float sf = rsqrtf(v + EPS) * g[t];
    sc[t] = sf;
    sh[t] = be[t] - m * sf;
  }
}

// ---------------- BN apply + ReLU: bf16 in -> fp32 out (nontemporal) ----------------
__global__ __launch_bounds__(256) void k_bnapply(const unsigned short* __restrict__ in,
                                                 float* __restrict__ outp,
                                                 const float* __restrict__ sc,
                                                 const float* __restrict__ sh) {
  int t = threadIdx.x;
  int lane = t & 63;
  int sub = t >> 6;
  float4 s4 = ((const float4*)sc)[lane];
  float4 h4 = ((const float4*)sh)[lane];
  for (int r = blockIdx.x * 4 + sub; r < N; r += gridDim.x * 4) {
    uint2 u = *(const uint2*)&in[(size_t)r * 256 + lane * 4];
    f32x4 v;
    v[0] = fmaxf(fmaf(bflo(u.x), s4.x, h4.x), 0.f);
    v[1] = fmaxf(fmaf(bfhi(u.x), s4.y, h4.y), 0.f);
    v[2] = fmaxf(fmaf(bflo(u.y), s4.z, h4.z), 0.f);
    v[3] = fmaxf(fmaf(bfhi(u.y), s4.w, h4.w), 0.f);
    __builtin_nontemporal_store(v, (f32x4*)&outp[(size_t)r * 256 + lane * 4]);
  }
}

// ---------------- launch ----------------
extern "C" void kernel_launch(void* const* d_in, const int* in_sizes, int n_in,
                              void* d_out, int out_size, void* d_ws, size_t ws_size,
                              hipStream_t stream) {
  const float* x  = (const float*)d_in[0];
  const void*  ei = d_in[1];
  const float* W1 = (const float*)d_in[2];
  const float* b1 = (const float*)d_in[3];
  const float* g1 = (const float*)d_in[4];
  const float* be1 = (const float*)d_in[5];
  const float* W2 = (const float*)d_in[6];
  const float* b2 = (const float*)d_in[7];
  const float* g2 = (const float*)d_in[8];
  const float* be2 = (const float*)d_in[9];
  float* out = (float*)d_out;

  char* base = (char*)d_ws;
  size_t off = 0;
  unsigned short* hbuf = (unsigned short*)(base + off); off += (size_t)N * D * 2;
  unsigned short* abuf = (unsigned short*)(base + off); off += (size_t)N * D * 2;
  unsigned short* Wf1 = (unsigned short*)(base + off);  off += (size_t)D * D * 2;
  unsigned short* Wf2 = (unsigned short*)(base + off);  off += (size_t)D * D * 2;
  // zero-init region (contiguous): degc + bn accumulators + tickets
  int*   degc = (int*)(base + off);    off += (size_t)N * 4;
  float* bnsum1 = (float*)(base + off); off += (size_t)D * 4;
  float* bnsq1  = (float*)(base + off); off += (size_t)D * 4;
  float* bnsum2 = (float*)(base + off); off += (size_t)D * 4;
  float* bnsq2  = (float*)(base + off); off += (size_t)D * 4;
  int*   cnt1 = (int*)(base + off);    off += 4;
  int*   cnt2 = (int*)(base + off);    off += 4;
  int*   sdone = (int*)(base + off);   off += 8;
  size_t zero_bytes = (size_t)N * 4 + 4 * (size_t)D * 4 + 16;
  float* dinv = (float*)(base + off); off += (size_t)N * 4;
  int*   offs = (int*)(base + off);   off += (size_t)(N + 4) * 4;
  int*   curs = (int*)(base + off);   off += (size_t)N * 4;
  int2*  epair = (int2*)(base + off); off += (size_t)(E + N) * 8;
  float* partial = (float*)(base + off); off += (size_t)AGG_BLOCKS * 512 * 4;  // 4 MB
  float* sc1 = (float*)(base + off);  off += (size_t)D * 4;
  float* sh1 = (float*)(base + off);  off += (size_t)D * 4;
  float* sc2 = (float*)(base + off);  off += (size_t)D * 4;
  float* sh2 = (float*)(base + off);  off += (size_t)D * 4;
  int*   bsum = (int*)(base + off);   off += 256 * 4;

  // ---- zero degc + BN accumulators + tickets ----
  (void)hipMemsetAsync(degc, 0, zero_bytes, stream);

  // ---- W repack overlapped with degree count (both low-VGPR, no LDS) ----
  k_wfrag_count<<<256 + CB64, 64, 0, stream>>>(W1, W2, Wf1, Wf2, ei, degc);

  // ---- GEMM1 (standalone; LDS-heavy blocks no longer throttle count) ----
  k_gemm1<<<GB, 256, 0, stream>>>(x, Wf1, hbuf);

  // ---- fused scan (partial + spin + final + self-loop fill) ----
  k_scan<<<NB, 256, 0, stream>>>(degc, dinv, offs, curs, epair, bsum, sdone);
  k_fill_edges<<<CB, 256, 0, stream>>>(ei, dinv, curs, epair);

  // ---- layer 1: aggregate (+stats) -> finalize sc1/sh1 ----
  k_agg<<<AGG_BLOCKS, 256, 0, stream>>>(hbuf, offs, epair, b1, abuf, partial);
  k_bnred<<<16, 256, 0, stream>>>(partial, bnsum1, bnsq1, cnt1, g1, be1, sc1, sh1);

  // ---- layer 2: fused(BN1+ReLU) GEMM -> aggregate (+stats) -> finalize -> apply ----
  k_gemm2<<<GB, 256, 0, stream>>>(abuf, Wf2, hbuf, sc1, sh1);
  k_agg<<<AGG_BLOCKS, 256, 0, stream>>>(hbuf, offs, epair, b2, abuf, partial);
  k_bnred<<<16, 256, 0, stream>>>(partial, bnsum2, bnsq2, cnt2, g2, be2, sc2, sh2);
  k_bnapply<<<512, 256, 0, stream>>>(abuf, out, sc2, sh2);
}

// Round 13
// 280.197 us; speedup vs baseline: 1.0954x; 1.0954x over previous
//
#include <hip/hip_runtime.h>
#include <cstdint>
#include <cstddef>

constexpr int N = 50000;
constexpr int E = 800000;
constexpr int D = 256;
constexpr float EPS = 1e-5f;
constexpr int NB = (N + 255) / 256;   // 196 scan blocks
constexpr int GB = (N + 63) / 64;     // 782 GEMM blocks
constexpr int CB = (E + 255) / 256;   // 3125 edge blocks
constexpr int AGG_BLOCKS = 2048;      // fixed agg grid (grid-stride)

// zero region: degc (N ints) + 4*D floats + 2 counters = 204112 B = 12757 int4
constexpr int ZTOT4 = (N * 4 + 4 * D * 4 + 16) / 16;   // int4 count
constexpr int ZBLK = (ZTOT4 + 63) / 64;                // 200 blocks of 64 threads

typedef __attribute__((ext_vector_type(8))) short short8;            // 8 bf16
typedef __attribute__((ext_vector_type(4))) float f32x4;             // MFMA acc

// ---- bf16 helpers ----
__device__ __forceinline__ unsigned short f2bf(float f) {  // RNE (scalar path)
  union { float f; unsigned u; } c; c.f = f;
  unsigned u = c.u;
  u += 0x7fff + ((u >> 16) & 1);
  return (unsigned short)(u >> 16);
}
__device__ __forceinline__ float bf2f(unsigned short h) {
  union { unsigned u; float f; } c; c.u = ((unsigned)h) << 16;
  return c.f;
}
__device__ __forceinline__ float bflo(unsigned u) {
  union { unsigned x; float f; } c; c.x = u << 16; return c.f;
}
__device__ __forceinline__ float bfhi(unsigned u) {
  union { unsigned x; float f; } c; c.x = u & 0xffff0000u; return c.f;
}
// HW packed convert: dst = bf16(lo) | bf16(hi)<<16  (RNE; 1 VALU per 2 values)
__device__ __forceinline__ unsigned cvt_pk(float lo, float hi) {
  unsigned r;
  asm("v_cvt_pk_bf16_f32 %0, %1, %2" : "=v"(r) : "v"(lo), "v"(hi));
  return r;
}
// nontemporal 8B edge-pair load (keeps the streamed edge list out of L2)
__device__ __forceinline__ int2 ldnt_pair(const int2* p) {
  unsigned long long v = __builtin_nontemporal_load((const unsigned long long*)p);
  int2 r;
  r.x = (int)(unsigned)(v & 0xffffffffull);
  r.y = (int)(unsigned)(v >> 32);
  return r;
}

// ---- inline edge-index dtype detection (per-wave, uniform) ----
__device__ __forceinline__ int detect64(const void* ei) {
  const int* p = (const int*)ei;
  int l = threadIdx.x & 63;
  int nz = (p[2 * l + 1] != 0) | (p[2 * l + 129] != 0);
  return __ballot(nz) == 0ULL;
}

__device__ __forceinline__ int edge_at(const void* ei, int is64, long long pos) {
  if (is64) return (int)((const long long*)ei)[pos];
  return ((const int*)ei)[pos];
}

// ---------------- GEMM body: C[64 rows x 256](bf16) = A @ W ----------------
template <bool A_BF16, bool FUSE_BN>
__device__ __forceinline__ void gemm_body(const void* __restrict__ Ap,
                                          const unsigned short* __restrict__ Wf,
                                          unsigned short* __restrict__ C,
                                          const float* __restrict__ sc,
                                          const float* __restrict__ sh,
                                          int bid) {
  __shared__ unsigned short As[64][264];   // [m][k] +8 pad; reused as Cs
  int t = threadIdx.x;
  int lane = t & 63;
  int w = t >> 6;
  int row0 = bid * 64;
  int l16 = lane & 15, lk = lane >> 4;

  f32x4 acc[4][4];
#pragma unroll
  for (int i = 0; i < 4; ++i)
#pragma unroll
    for (int j = 0; j < 4; ++j) acc[i][j] = (f32x4){0.f, 0.f, 0.f, 0.f};

  int arow = t >> 2;          // 0..63
  int ak0 = (t & 3) * 8;      // 0,8,16,24
  int gr = row0 + arow;
  bool inb = (gr < N);

#pragma unroll
  for (int ks = 0; ks < 8; ++ks) {
    int kc = ks * 32 + ak0;
    float f[8] = {0.f, 0.f, 0.f, 0.f, 0.f, 0.f, 0.f, 0.f};
    if (inb) {
      if (A_BF16) {
        const unsigned short* A = (const unsigned short*)Ap;
        short8 v = *(const short8*)&A[(size_t)gr * 256 + kc];
#pragma unroll
        for (int j = 0; j < 8; ++j) f[j] = bf2f((unsigned short)v[j]);
      } else {
        const float* A = (const float*)Ap;
        float4 f0 = *(const float4*)&A[(size_t)gr * 256 + kc];
        float4 f1 = *(const float4*)&A[(size_t)gr * 256 + kc + 4];
        f[0] = f0.x; f[1] = f0.y; f[2] = f0.z; f[3] = f0.w;
        f[4] = f1.x; f[5] = f1.y; f[6] = f1.z; f[7] = f1.w;
      }
    }
    if (FUSE_BN) {
#pragma unroll
      for (int j = 0; j < 8; ++j)
        f[j] = fmaxf(fmaf(f[j], sc[kc + j], sh[kc + j]), 0.f);
    }
    uint4 pk;
    pk.x = cvt_pk(f[0], f[1]);
    pk.y = cvt_pk(f[2], f[3]);
    pk.z = cvt_pk(f[4], f[5]);
    pk.w = cvt_pk(f[6], f[7]);
    *(uint4*)&As[arow][kc] = pk;
  }
  __syncthreads();

#pragma unroll
  for (int ks = 0; ks < 8; ++ks) {
    short8 af[4];
#pragma unroll
    for (int mf = 0; mf < 4; ++mf)
      af[mf] = *(const short8*)&As[mf * 16 + l16][ks * 32 + lk * 8];
#pragma unroll
    for (int nf = 0; nf < 4; ++nf) {
      short8 bf = *(const short8*)&Wf[(((size_t)ks * 16 + w * 4 + nf) * 64 + lane) * 8];
#pragma unroll
      for (int mf = 0; mf < 4; ++mf)
        acc[mf][nf] = __builtin_amdgcn_mfma_f32_16x16x32_bf16(af[mf], bf, acc[mf][nf], 0, 0, 0);
    }
  }
  __syncthreads();  // As reads done; safe to alias as Cs

  unsigned short(*Cs)[264] = As;
#pragma unroll
  for (int mf = 0; mf < 4; ++mf)
#pragma unroll
    for (int nf = 0; nf < 4; ++nf)
#pragma unroll
      for (int r = 0; r < 4; ++r)
        Cs[mf * 16 + lk * 4 + r][w * 64 + nf * 16 + l16] = f2bf(acc[mf][nf][r]);
  __syncthreads();
#pragma unroll
  for (int it = 0; it < 8; ++it) {
    int r = it * 8 + (t >> 5);
    int gr2 = row0 + r;
    if (gr2 < N)
      *(short8*)&C[(size_t)gr2 * 256 + (t & 31) * 8] = *(const short8*)&Cs[r][(t & 31) * 8];
  }
}

// ---------------- merged: GEMM1 (independent) + degree count ----------------
__global__ __launch_bounds__(256) void k_gemm1_count(const float* __restrict__ x,
                                                     const unsigned short* __restrict__ Wf1,
                                                     unsigned short* __restrict__ hbuf,
                                                     const void* __restrict__ ei,
                                                     int* __restrict__ degc) {
  if (blockIdx.x < GB) {
    gemm_body<false, false>(x, Wf1, hbuf, nullptr, nullptr, blockIdx.x);
  } else {
    int is64 = detect64(ei);
    int e = (blockIdx.x - GB) * 256 + threadIdx.x;
    if (e >= E) return;
    int c = edge_at(ei, is64, (long long)E + e);
    atomicAdd(&degc[c], 1);
  }
}

// ---------------- GEMM layer 2 (fused BN1+ReLU on A) ----------------
__global__ __launch_bounds__(256) void k_gemm2(const unsigned short* __restrict__ A,
                                               const unsigned short* __restrict__ Wf,
                                               unsigned short* __restrict__ C,
                                               const float* __restrict__ sc,
                                               const float* __restrict__ sh) {
  gemm_body<true, true>(A, Wf, C, sc, sh, blockIdx.x);
}

// ---------------- scan stage 1 (+ dinv fused) ----------------
__global__ void k_scan_partial(const int* __restrict__ degc, int* __restrict__ bsum,
                               float* __restrict__ dinv) {
  __shared__ int sd[256];
  int t = threadIdx.x;
  int i = blockIdx.x * 256 + t;
  int dv = (i < N) ? degc[i] : 0;
  if (i < N) dinv[i] = rsqrtf((float)(dv + 1));
  int v = (i < N) ? (dv + 1) : 0;
  sd[t] = v;
  __syncthreads();
  for (int s = 128; s > 0; s >>= 1) {
    if (t < s) sd[t] += sd[t + s];
    __syncthreads();
  }
  if (t == 0) bsum[blockIdx.x] = sd[0];
}

// ---------------- scan final (block-scan folded in; + self-loop fill) ----------------
__global__ void k_scan_final(const int* __restrict__ degc, const int* __restrict__ bsum,
                             const float* __restrict__ dinv, int* __restrict__ offs,
                             int* __restrict__ curs, int2* __restrict__ epair) {
  __shared__ int sb[256];
  __shared__ int sd[256];
  int t = threadIdx.x;
  int bv = (t < NB) ? bsum[t] : 0;
  sb[t] = bv;
  __syncthreads();
  for (int off = 1; off < 256; off <<= 1) {
    int x = (t >= off) ? sb[t - off] : 0;
    __syncthreads();
    sb[t] += x;
    __syncthreads();
  }
  int base = sb[blockIdx.x] - bsum[blockIdx.x];
  int i = blockIdx.x * 256 + t;
  int v = (i < N) ? (degc[i] + 1) : 0;
  sd[t] = v;
  __syncthreads();
  for (int off = 1; off < 256; off <<= 1) {
    int x = (t >= off) ? sd[t - off] : 0;
    __syncthreads();
    sd[t] += x;
    __syncthreads();
  }
  if (i < N) {
    int o = base + sd[t] - v;
    offs[i] = o;
    curs[i] = o + 1;
    float d = dinv[i];
    epair[o] = make_int2(i, __float_as_int(d * d));  // self loop
  }
  if (i == N - 1) offs[N] = base + sd[t];
}

__global__ void k_fill_edges(const void* __restrict__ ei,
                             const float* __restrict__ dinv, int* __restrict__ curs,
                             int2* __restrict__ epair) {
  int is64 = detect64(ei);
  int e = blockIdx.x * 256 + threadIdx.x;
  if (e >= E) return;
  int r = edge_at(ei, is64, e);
  int c = edge_at(ei, is64, (long long)E + e);
  int p = atomicAdd(&curs[c], 1);
  epair[p] = make_int2(r, __float_as_int(dinv[r] * dinv[c]));
}

// ---------------- W repack (both weights) + zero-region init ----------------
// blocks [0,256): repack; blocks [256, 256+ZBLK): zero degc+BN accumulators.
__global__ void k_wfrag(const float* __restrict__ W1, const float* __restrict__ W2,
                        unsigned short* __restrict__ Wf1, unsigned short* __restrict__ Wf2,
                        int4* __restrict__ zbase) {
  int b = blockIdx.x;
  if (b >= 256) {
    int idx4 = (b - 256) * 64 + threadIdx.x;
    if (idx4 < ZTOT4) zbase[idx4] = make_int4(0, 0, 0, 0);
    return;
  }
  const float* W = (b < 128) ? W1 : W2;
  unsigned short* Wf = (b < 128) ? Wf1 : Wf2;
  int tile = b & 127;
  int lane = threadIdx.x;     // 64
  int kstep = tile >> 4, wn = tile & 15;
  int kbase = kstep * 32 + (lane >> 4) * 8;
  int col = wn * 16 + (lane & 15);
  float f[8];
#pragma unroll
  for (int j = 0; j < 8; ++j) f[j] = W[(size_t)(kbase + j) * 256 + col];
  uint4 pk;
  pk.x = cvt_pk(f[0], f[1]);
  pk.y = cvt_pk(f[2], f[3]);
  pk.z = cvt_pk(f[4], f[5]);
  pk.w = cvt_pk(f[6], f[7]);
  *(uint4*)&Wf[(((size_t)tile) * 64 + lane) * 8] = pk;
}

// ---------------- aggregation + fused BN column stats ----------------
// 1 wave/node, lane = 4 cols (8B gather), 8-deep nt epair unroll; grid-stride
// with fused per-lane column sum/sumsq -> partial[block][512].
__global__ __launch_bounds__(256) void k_agg(const unsigned short* __restrict__ h,
                                             const int* __restrict__ offs,
                                             const int2* __restrict__ epair,
                                             const float* __restrict__ bias,
                                             unsigned short* __restrict__ outp,
                                             float* __restrict__ partial) {
  int t = threadIdx.x;
  int wv = t >> 6;
  int lane = t & 63;
  float4 bb = ((const float4*)bias)[lane];
  float s0 = 0.f, s1 = 0.f, s2 = 0.f, s3 = 0.f;
  float q0 = 0.f, q1 = 0.f, q2 = 0.f, q3 = 0.f;

#define ACC4(v, wgt)                         \
  do {                                       \
    a0 = fmaf(wgt, bflo((v).x), a0);         \
    a1 = fmaf(wgt, bfhi((v).x), a1);         \
    a2 = fmaf(wgt, bflo((v).y), a2);         \
    a3 = fmaf(wgt, bfhi((v).y), a3);         \
  } while (0)

  for (int nd0 = blockIdx.x * 4; nd0 < N; nd0 += AGG_BLOCKS * 4) {
    int nd = nd0 + wv;
    if (nd < N) {
      int node = __builtin_amdgcn_readfirstlane(nd);  // wave-uniform
      int e = offs[node];
      int end = offs[node + 1];
      float a0 = 0.f, a1 = 0.f, a2 = 0.f, a3 = 0.f;

      for (; e + 8 <= end; e += 8) {
        int2 p0 = ldnt_pair(&epair[e + 0]), p1 = ldnt_pair(&epair[e + 1]);
        int2 p2 = ldnt_pair(&epair[e + 2]), p3 = ldnt_pair(&epair[e + 3]);
        int2 p4 = ldnt_pair(&epair[e + 4]), p5 = ldnt_pair(&epair[e + 5]);
        int2 p6 = ldnt_pair(&epair[e + 6]), p7 = ldnt_pair(&epair[e + 7]);
        uint2 v0 = *(const uint2*)&h[(size_t)p0.x * 256 + lane * 4];
        uint2 v1 = *(const uint2*)&h[(size_t)p1.x * 256 + lane * 4];
        uint2 v2 = *(const uint2*)&h[(size_t)p2.x * 256 + lane * 4];
        uint2 v3 = *(const uint2*)&h[(size_t)p3.x * 256 + lane * 4];
        uint2 v4 = *(const uint2*)&h[(size_t)p4.x * 256 + lane * 4];
        uint2 v5 = *(const uint2*)&h[(size_t)p5.x * 256 + lane * 4];
        uint2 v6 = *(const uint2*)&h[(size_t)p6.x * 256 + lane * 4];
        uint2 v7 = *(const uint2*)&h[(size_t)p7.x * 256 + lane * 4];
        ACC4(v0, __int_as_float(p0.y));
        ACC4(v1, __int_as_float(p1.y));
        ACC4(v2, __int_as_float(p2.y));
        ACC4(v3, __int_as_float(p3.y));
        ACC4(v4, __int_as_float(p4.y));
        ACC4(v5, __int_as_float(p5.y));
        ACC4(v6, __int_as_float(p6.y));
        ACC4(v7, __int_as_float(p7.y));
      }
      if (e < end) {
#pragma unroll
        for (int k = 0; k < 8; ++k) {
          int idx = e + k;
          bool act = (idx < end);
          int2 p = ldnt_pair(&epair[act ? idx : end - 1]);  // deg >= 1
          float wgt = act ? __int_as_float(p.y) : 0.f;
          uint2 v = *(const uint2*)&h[(size_t)p.x * 256 + lane * 4];
          ACC4(v, wgt);
        }
      }

      uint2 ov;
      ov.x = cvt_pk(a0 + bb.x, a1 + bb.y);
      ov.y = cvt_pk(a2 + bb.z, a3 + bb.w);
      *(uint2*)&outp[(size_t)nd * 256 + lane * 4] = ov;
      float f0 = bflo(ov.x), f1 = bfhi(ov.x), f2v = bflo(ov.y), f3 = bfhi(ov.y);
      s0 += f0; q0 = fmaf(f0, f0, q0);
      s1 += f1; q1 = fmaf(f1, f1, q1);
      s2 += f2v; q2 = fmaf(f2v, f2v, q2);
      s3 += f3; q3 = fmaf(f3, f3, q3);
    }
  }
#undef ACC4

  __shared__ float4 ps[256];
  __shared__ float4 pq[256];
  ps[t] = {s0, s1, s2, s3};
  pq[t] = {q0, q1, q2, q3};
  __syncthreads();
  float* pout = partial + (size_t)blockIdx.x * 512;
  if (t < 64) {
    float4 a = ps[t], b = ps[64 + t], c = ps[128 + t], d = ps[192 + t];
    float4 o = {a.x + b.x + c.x + d.x, a.y + b.y + c.y + d.y,
                a.z + b.z + c.z + d.z, a.w + b.w + c.w + d.w};
    ((float4*)pout)[t] = o;
  } else if (t < 128) {
    int l = t - 64;
    float4 a = pq[l], b = pq[64 + l], c = pq[128 + l], d = pq[192 + l];
    float4 o = {a.x + b.x + c.x + d.x, a.y + b.y + c.y + d.y,
                a.z + b.z + c.z + d.z, a.w + b.w + c.w + d.w};
    ((float4*)(pout + 256))[l] = o;
  }
}

// ---------------- BN stats reduce + last-block finalize ----------------
__global__ __launch_bounds__(256) void k_bnred(const float* __restrict__ partial,
                                               float* __restrict__ bnsum,
                                               float* __restrict__ bnsq,
                                               int* __restrict__ cnt,
                                               const float* __restrict__ g,
                                               const float* __restrict__ be,
                                               float* __restrict__ sc,
                                               float* __restrict__ sh) {
  int t = threadIdx.x;
  float s = 0.f, q = 0.f;
  int b0 = blockIdx.x * (AGG_BLOCKS / 16);
  for (int b = b0; b < b0 + AGG_BLOCKS / 16; ++b) {
    s += partial[(size_t)b * 512 + t];
    q += partial[(size_t)b * 512 + 256 + t];
  }
  atomicAdd(&bnsum[t], s);
  atomicAdd(&bnsq[t], q);
  __threadfence();
  __shared__ int last;
  if (t == 0) last = (atomicAdd(cnt, 1) == 15);
  __syncthreads();
  if (last) {
    float S = atomicAdd(&bnsum[t], 0.f);  // device-coherent read
    float Q = atomicAdd(&bnsq[t], 0.f);
    const float inv = 1.f / (float)N;
    float m = S * inv;
    float v = Q * inv - m * m;
    float sf = rsqrtf(v + EPS) * g[t];
    sc[t] = sf;
    sh[t] = be[t] - m * sf;
  }
}

// ---------------- BN apply + ReLU: bf16 in -> fp32 out ----------------
__global__ __launch_bounds__(256) void k_bnapply(const unsigned short* __restrict__ in,
                                                 float* __restrict__ outp,
                                                 const float* __restrict__ sc,
                                                 const float* __restrict__ sh) {
  int t = threadIdx.x;
  int lane = t & 63;
  int sub = t >> 6;
  float4 s4 = ((const float4*)sc)[lane];
  float4 h4 = ((const float4*)sh)[lane];
  for (int r = blockIdx.x * 4 + sub; r < N; r += gridDim.x * 4) {
    uint2 u = *(const uint2*)&in[(size_t)r * 256 + lane * 4];
    float4 v;
    v.x = fmaxf(fmaf(bflo(u.x), s4.x, h4.x), 0.f);
    v.y = fmaxf(fmaf(bfhi(u.x), s4.y, h4.y), 0.f);
    v.z = fmaxf(fmaf(bflo(u.y), s4.z, h4.z), 0.f);
    v.w = fmaxf(fmaf(bfhi(u.y), s4.w, h4.w), 0.f);
    *(float4*)&outp[(size_t)r * 256 + lane * 4] = v;
  }
}

// ---------------- launch ----------------
extern "C" void kernel_launch(void* const* d_in, const int* in_sizes, int n_in,
                              void* d_out, int out_size, void* d_ws, size_t ws_size,
                              hipStream_t stream) {
  const float* x  = (const float*)d_in[0];
  const void*  ei = d_in[1];
  const float* W1 = (const float*)d_in[2];
  const float* b1 = (const float*)d_in[3];
  const float* g1 = (const float*)d_in[4];
  const float* be1 = (const float*)d_in[5];
  const float* W2 = (const float*)d_in[6];
  const float* b2 = (const float*)d_in[7];
  const float* g2 = (const float*)d_in[8];
  const float* be2 = (const float*)d_in[9];
  float* out = (float*)d_out;

  char* base = (char*)d_ws;
  size_t off = 0;
  unsigned short* hbuf = (unsigned short*)(base + off); off += (size_t)N * D * 2;
  unsigned short* abuf = (unsigned short*)(base + off); off += (size_t)N * D * 2;
  unsigned short* Wf1 = (unsigned short*)(base + off);  off += (size_t)D * D * 2;
  unsigned short* Wf2 = (unsigned short*)(base + off);  off += (size_t)D * D * 2;
  // zero-init region (contiguous): degc + bnsum1/bnsq1/bnsum2/bnsq2 + cnt1/cnt2
  int*   degc = (int*)(base + off);    off += (size_t)N * 4;
  float* bnsum1 = (float*)(base + off); off += (size_t)D * 4;
  float* bnsq1  = (float*)(base + off); off += (size_t)D * 4;
  float* bnsum2 = (float*)(base + off); off += (size_t)D * 4;
  float* bnsq2  = (float*)(base + off); off += (size_t)D * 4;
  int*   cnt1 = (int*)(base + off);    off += 8;
  int*   cnt2 = (int*)(base + off);    off += 8;
  float* dinv = (float*)(base + off); off += (size_t)N * 4;
  int*   offs = (int*)(base + off);   off += (size_t)(N + 4) * 4;
  int*   curs = (int*)(base + off);   off += (size_t)N * 4;
  int2*  epair = (int2*)(base + off); off += (size_t)(E + N) * 8;
  float* partial = (float*)(base + off); off += (size_t)AGG_BLOCKS * 512 * 4;  // 4 MB
  float* sc1 = (float*)(base + off);  off += (size_t)D * 4;
  float* sh1 = (float*)(base + off);  off += (size_t)D * 4;
  float* sc2 = (float*)(base + off);  off += (size_t)D * 4;
  float* sh2 = (float*)(base + off);  off += (size_t)D * 4;
  int*   bsum = (int*)(base + off);   off += 256 * 4;

  // ---- W repack + zero-init (one launch) ----
  k_wfrag<<<256 + ZBLK, 64, 0, stream>>>(W1, W2, Wf1, Wf2, (int4*)degc);

  // ---- GEMM1 overlapped with degree count (independent work) ----
  k_gemm1_count<<<GB + CB, 256, 0, stream>>>(x, Wf1, hbuf, ei, degc);

  // ---- rest of graph build ----
  k_scan_partial<<<NB, 256, 0, stream>>>(degc, bsum, dinv);
  k_scan_final<<<NB, 256, 0, stream>>>(degc, bsum, dinv, offs, curs, epair);
  k_fill_edges<<<CB, 256, 0, stream>>>(ei, dinv, curs, epair);

  // ---- layer 1: aggregate (+stats) -> finalize sc1/sh1 ----
  k_agg<<<AGG_BLOCKS, 256, 0, stream>>>(hbuf, offs, epair, b1, abuf, partial);
  k_bnred<<<16, 256, 0, stream>>>(partial, bnsum1, bnsq1, cnt1, g1, be1, sc1, sh1);

  // ---- layer 2: fused(BN1+ReLU) GEMM -> aggregate (+stats) -> finalize -> apply ----
  k_gemm2<<<GB, 256, 0, stream>>>(abuf, Wf2, hbuf, sc1, sh1);
  k_agg<<<AGG_BLOCKS, 256, 0, stream>>>(hbuf, offs, epair, b2, abuf, partial);
  k_bnred<<<16, 256, 0, stream>>>(partial, bnsum2, bnsq2, cnt2, g2, be2, sc2, sh2);
  k_bnapply<<<512, 256, 0, stream>>>(abuf, out, sc2, sh2);
}